// Round 7
// baseline (73271.161 us; speedup 1.0000x reference)
//
#include <hip/hip_runtime.h>

typedef unsigned long long u64;
typedef unsigned int u32;
typedef unsigned short ushort_t;

#define BB 16
#define TT 1500
#define NG3 1536
#define GM (BB * TT)   /* 24000 */
#define GK 512
#define LNEPS 1e-5f
#define NCW 96         /* compute WGs per layer */
#define FL 64          /* flag line stride in uints (256B) */
#define HSLOT 4096     /* u64 per Hb0 ring slot: 16 rows * 256 */

// ---------------- helpers ----------------
__device__ __forceinline__ float sigmoidf_(float x) { return 1.f / (1.f + __expf(-x)); }
__device__ __forceinline__ float tanhf_(float x) {
  x = fminf(15.f, fmaxf(-15.f, x));
  float e = __expf(2.f * x);
  return (e - 1.f) / (e + 1.f);
}
__device__ __forceinline__ float red16_(float v) {
  v += __shfl_xor(v, 1, 64); v += __shfl_xor(v, 2, 64);
  v += __shfl_xor(v, 4, 64); v += __shfl_xor(v, 8, 64);
  return v;
}
// bf16 pair unpack (bf16 = high 16 bits of f32)
__device__ __forceinline__ float blo(u32 u) { return __uint_as_float(u << 16); }
__device__ __forceinline__ float bhi(u32 u) { return __uint_as_float(u & 0xffff0000u); }
// RNE pack two f32 -> bf16x2
__device__ __forceinline__ u32 bpack(float a, float b) {
  u32 ua = __float_as_uint(a); ua = (ua + 0x7fffu + ((ua >> 16) & 1u)) >> 16;
  u32 ub = __float_as_uint(b); ub = (ub + 0x7fffu + ((ub >> 16) & 1u)) >> 16;
  return ua | (ub << 16);
}
// 16B-chunk bank swizzle within a 64-chunk row: bijective per 8-chunk block
__device__ __forceinline__ int pc16(int c) { return c ^ ((c >> 3) & 7); }

__device__ __forceinline__ u64 ldA(const u64* p) {
  return __hip_atomic_load(p, __ATOMIC_RELAXED, __HIP_MEMORY_SCOPE_AGENT);
}
__device__ __forceinline__ void stA8(u64* p, u64 v) {
  __hip_atomic_store(p, v, __ATOMIC_RELAXED, __HIP_MEMORY_SCOPE_AGENT);
}
__device__ __forceinline__ u32 ldA32(const u32* p) {
  return __hip_atomic_load(p, __ATOMIC_RELAXED, __HIP_MEMORY_SCOPE_AGENT);
}
__device__ __forceinline__ void stA32(u32* p, u32 v) {
  __hip_atomic_store(p, v, __ATOMIC_RELAXED, __HIP_MEMORY_SCOPE_AGENT);
}
__device__ __forceinline__ u64 pk(u32 tag, u32 bits) {
  return ((u64)tag << 32) | (u64)bits;
}

#define MAC8(U, W, P) do { \
  P = fmaf(blo((U).x), (W)[0], P); P = fmaf(bhi((U).x), (W)[1], P); \
  P = fmaf(blo((U).y), (W)[2], P); P = fmaf(bhi((U).y), (W)[3], P); \
  P = fmaf(blo((U).z), (W)[4], P); P = fmaf(bhi((U).z), (W)[5], P); \
  P = fmaf(blo((U).w), (W)[6], P); P = fmaf(bhi((U).w), (W)[7], P); } while (0)

// ---------------- big GEMM: C[M,N] = A[M,K] @ W[N,K]^T (fp32) ----------------
__global__ __launch_bounds__(256) void gemm_nt(const float* __restrict__ A,
                                               const float* __restrict__ W,
                                               float* __restrict__ C) {
  __shared__ __align__(16) float As[32][68];
  __shared__ __align__(16) float Ws[32][68];
  const int m0 = blockIdx.x * 64;
  const int n0 = blockIdx.y * 64;
  const int tid = threadIdx.x;
  const int tm = tid & 15, tn = tid >> 4;
  float acc[4][4] = {};
  for (int k0 = 0; k0 < GK; k0 += 32) {
#pragma unroll
    for (int u = 0; u < 2; ++u) {
      int idx = tid + u * 256;
      int r = idx >> 3;
      int kq = (idx & 7) * 4;
      float4 a = *reinterpret_cast<const float4*>(&A[(size_t)(m0 + r) * GK + k0 + kq]);
      As[kq + 0][r] = a.x; As[kq + 1][r] = a.y; As[kq + 2][r] = a.z; As[kq + 3][r] = a.w;
      float4 w = *reinterpret_cast<const float4*>(&W[(size_t)(n0 + r) * GK + k0 + kq]);
      Ws[kq + 0][r] = w.x; Ws[kq + 1][r] = w.y; Ws[kq + 2][r] = w.z; Ws[kq + 3][r] = w.w;
    }
    __syncthreads();
#pragma unroll
    for (int kk = 0; kk < 32; ++kk) {
      float a[4], w[4];
      *reinterpret_cast<float4*>(a) = *reinterpret_cast<const float4*>(&As[kk][tm * 4]);
      *reinterpret_cast<float4*>(w) = *reinterpret_cast<const float4*>(&Ws[kk][tn * 4]);
#pragma unroll
      for (int i = 0; i < 4; ++i)
#pragma unroll
        for (int q = 0; q < 4; ++q)
          acc[i][q] = fmaf(a[i], w[q], acc[i][q]);
    }
    __syncthreads();
  }
#pragma unroll
  for (int i = 0; i < 4; ++i) {
    float4 v = make_float4(acc[i][0], acc[i][1], acc[i][2], acc[i][3]);
    *reinterpret_cast<float4*>(&C[(size_t)(m0 + tm * 4 + i) * NG3 + n0 + tn * 4]) = v;
  }
}

// ---------------- fused 2-layer GRU scan (tagged data, bf16 h) ----------------
// WG 0..95  : layer 0 (16 cols each, Wh0 f32 in regs)
// WG 96..191: layer 1 (16 cols, Wi1+Wh1 f32 in regs, dual matvec)
// G0 u64[2][16][1536] fp32-tagged gates; G1 u64[2][16][2048] (1536.. = x_n).
// Hb0 u64[4][16][256]: tagged bf16x2 h0 ring L0->L1; prog1: L1 copy progress.
__global__ __launch_bounds__(256, 1) void gru_fused(
    const float* __restrict__ Wh0, const float* __restrict__ Wi1,
    const float* __restrict__ Wh1, const float* __restrict__ X0,
    const float* __restrict__ lnw, const float* __restrict__ lnb,
    float* __restrict__ out, u64* __restrict__ G0, u64* __restrict__ G1,
    u64* __restrict__ Hb0, u32* __restrict__ prog1) {
  __shared__ __align__(16) ushort_t shA[BB][544];  // this layer's h (bf16, swizzled)
  __shared__ __align__(16) ushort_t shB[BB][544];  // L1: h0(t) (bf16, swizzled)

  const int tid = threadIdx.x, wg = blockIdx.x;
  const int lane = tid & 63, wv = tid >> 6;
  const int ks = lane & 15, cq = lane >> 4;   // matvec: K-chunk / col-in-wave
  const int b2 = wv * 4 + (lane >> 4);        // phase-2: batch row
  const int l16 = lane & 15;
  const int rr = tid >> 4, q16 = tid & 15;    // h0-copy: row / 32-col group

  const bool L1 = wg >= NCW;
  const int wgl = L1 ? wg - NCW : wg;
  const int col = wgl * 16 + wv * 4 + cq;

  float wh[32], wi[32];
  {
    const float* Wp = (L1 ? Wh1 : Wh0) + (size_t)col * 512 + ks * 32;
#pragma unroll
    for (int q = 0; q < 8; ++q) *(float4*)&wh[q * 4] = *(const float4*)&Wp[q * 4];
    if (L1) {
      const float* Wq = Wi1 + (size_t)col * 512 + ks * 32;
#pragma unroll
      for (int q = 0; q < 8; ++q) *(float4*)&wi[q * 4] = *(const float4*)&Wq[q * 4];
    } else {
#pragma unroll
      for (int q = 0; q < 32; ++q) wi[q] = 0.f;
    }
  }
  for (int idx = tid; idx < BB * 544; idx += 256) {
    (&shA[0][0])[idx] = 0; (&shB[0][0])[idx] = 0;
  }
  __syncthreads();

  u64* Gb = L1 ? G1 : G0;
  const int GW = L1 ? 2048 : 1536;
  const float* lnwL = lnw + (L1 ? 1536 : 0);
  const float* lnbL = lnb + (L1 ? 1536 : 0);

  for (int t = 0; t < TT; ++t) {
    const u32 want = (u32)(t + 1);
    float xv = 0.f;

    if (!L1) {
      // writers throttle h0-ring overwrite on L1 copy progress (3-step slack)
      if (wgl < BB && t >= 4) {
        if (tid < NCW) {
          const u32 w2 = (u32)(t - 3);
          while (ldA32(&prog1[(size_t)tid * FL]) < w2) __builtin_amdgcn_s_sleep(4);
        }
        __syncthreads();
      }
      if (col < 1024) xv = X0[((size_t)ks * TT + t) * NG3 + col];
    } else {
      // ---- poll + copy h0(t) ring slot -> shB (bf16 payload) ----
      const u64* src = Hb0 + (size_t)(t & 3) * HSLOT + (size_t)rr * 256 + q16 * 16;
      u32 pl[16];
      for (;;) {
        u32 bad = 0;
#pragma unroll
        for (int m = 0; m < 16; ++m) {
          u64 w = ldA(src + m);
          pl[m] = (u32)w;
          bad |= (u32)(w >> 32) ^ want;
        }
        if (!bad) break;
        __builtin_amdgcn_s_sleep(1);
      }
#pragma unroll
      for (int w = 0; w < 4; ++w)
        *reinterpret_cast<uint4*>(&shB[rr][pc16(q16 * 4 + w) * 8]) =
            make_uint4(pl[4 * w], pl[4 * w + 1], pl[4 * w + 2], pl[4 * w + 3]);
      __syncthreads();
      if (tid == 0) stA32(&prog1[(size_t)wgl * FL], want);
    }

    // ---- phase 1: matvec(s) over bf16 LDS h ----
    float gh = 0.f, gx = 0.f;
#pragma unroll 2
    for (int b = 0; b < 16; ++b) {
      float p = 0.f, p2 = 0.f;
#pragma unroll
      for (int j = 0; j < 4; ++j) {
        const int pc = pc16(ks * 4 + j);
        uint4 ua = *reinterpret_cast<const uint4*>(&shA[b][pc * 8]);
        MAC8(ua, &wh[8 * j], p);
        if (L1) {
          uint4 ub = *reinterpret_cast<const uint4*>(&shB[b][pc * 8]);
          MAC8(ub, &wi[8 * j], p2);
        }
      }
      p = red16_(p);
      if (L1) p2 = red16_(p2);
      if (ks == b) { gh = p; gx = p2; }
    }
    // ---- tagged gate store (fp32 payload) ----
    {
      u64* Gw = Gb + (size_t)(t & 1) * (BB * GW) + (size_t)ks * GW;
      if (!L1) {
        stA8(&Gw[col], pk(want, __float_as_uint(gh + xv)));
      } else if (col < 1024) {
        stA8(&Gw[col], pk(want, __float_as_uint(gh + gx)));
      } else {
        stA8(&Gw[col], pk(want, __float_as_uint(gh)));        // h_n
        stA8(&Gw[col + 512], pk(want, __float_as_uint(gx)));  // x_n
      }
    }

    // ---- phase 2: redundant LN + gates + h update ----
    const u64* Grow = Gb + (size_t)(t & 1) * (BB * GW) + (size_t)b2 * GW;

    // L0: prefetch x_n (plain cached) before polls
    float xn[32];
    if (!L1) {
      const float* Xr = X0 + ((size_t)b2 * TT + t) * NG3 + 1024;
#pragma unroll
      for (int seg = 0; seg < 4; ++seg) {
        *(float4*)&xn[seg * 8]     = *(const float4*)&Xr[seg * 128 + l16 * 8];
        *(float4*)&xn[seg * 8 + 4] = *(const float4*)&Xr[seg * 128 + l16 * 8 + 4];
      }
    }

    // fused r+z poll (one round trip)
    float gr[32], gz[32];
    for (;;) {
      u32 bad = 0;
#pragma unroll
      for (int seg = 0; seg < 4; ++seg) {
        const u64* pr = Grow + seg * 128 + l16 * 8;
#pragma unroll
        for (int e = 0; e < 8; ++e) {
          u64 a = ldA(pr + e);
          u64 b = ldA(pr + 512 + e);
          gr[seg * 8 + e] = __uint_as_float((u32)a);
          gz[seg * 8 + e] = __uint_as_float((u32)b);
          bad |= ((u32)(a >> 32) ^ want) | ((u32)(b >> 32) ^ want);
        }
      }
      if (!bad) break;
      __builtin_amdgcn_s_sleep(1);
    }

    float s = 0.f, s2 = 0.f;
#pragma unroll
    for (int k = 0; k < 32; ++k) { s += gr[k]; s2 += gr[k] * gr[k]; }
    s = red16_(s); s2 = red16_(s2);
    const float mr = s * (1.f / 512.f);
    const float rsr = rsqrtf(s2 * (1.f / 512.f) - mr * mr + LNEPS);
    float rv[32];
#pragma unroll
    for (int seg = 0; seg < 4; ++seg)
#pragma unroll
      for (int e = 0; e < 8; ++e) {
        int k = seg * 8 + e, j = seg * 128 + l16 * 8 + e;
        rv[k] = sigmoidf_((gr[k] - mr) * rsr * lnwL[j] + lnbL[j]);
      }

    s = 0.f; s2 = 0.f;
#pragma unroll
    for (int k = 0; k < 32; ++k) { s += gz[k]; s2 += gz[k] * gz[k]; }
    s = red16_(s); s2 = red16_(s2);
    const float mz = s * (1.f / 512.f);
    const float rsz = rsqrtf(s2 * (1.f / 512.f) - mz * mz + LNEPS);
    float zv[32];
#pragma unroll
    for (int seg = 0; seg < 4; ++seg)
#pragma unroll
      for (int e = 0; e < 8; ++e) {
        int k = seg * 8 + e, j = seg * 128 + l16 * 8 + e;
        zv[k] = sigmoidf_((gz[k] - mz) * rsz * lnwL[512 + j] + lnbL[512 + j]);
      }

    // n-row poll (h_n, + x_n for L1), consumed inline into np
    float np[32];
    for (;;) {
      u32 bad = 0;
#pragma unroll
      for (int seg = 0; seg < 4; ++seg) {
        const u64* pn = Grow + 1024 + seg * 128 + l16 * 8;
#pragma unroll
        for (int e = 0; e < 8; ++e) {
          int k = seg * 8 + e;
          u64 a = ldA(pn + e);
          float hnv = __uint_as_float((u32)a);
          bad |= (u32)(a >> 32) ^ want;
          float xnv;
          if (L1) {
            u64 b = ldA(pn + 512 + e);
            xnv = __uint_as_float((u32)b);
            bad |= (u32)(b >> 32) ^ want;
          } else {
            xnv = xn[k];
          }
          np[k] = xnv + rv[k] * hnv;
        }
      }
      if (!bad) break;
      __builtin_amdgcn_s_sleep(1);
    }

    s = 0.f; s2 = 0.f;
#pragma unroll
    for (int k = 0; k < 32; ++k) { s += np[k]; s2 += np[k] * np[k]; }
    s = red16_(s); s2 = red16_(s2);
    const float mn = s * (1.f / 512.f);
    const float rsn = rsqrtf(s2 * (1.f / 512.f) - mn * mn + LNEPS);

    // final gates + h update, bf16 write-back
#pragma unroll
    for (int seg = 0; seg < 4; ++seg) {
      const int pc = pc16(seg * 16 + l16);
      uint4 ho = *reinterpret_cast<const uint4*>(&shA[b2][pc * 8]);
      uint4 rs;
      if (L1) rs = *reinterpret_cast<const uint4*>(&shB[b2][pc * 8]);
      u32 hq[4] = {ho.x, ho.y, ho.z, ho.w};
      u32 rq[4] = {rs.x, rs.y, rs.z, rs.w};
      u32 outq[4];
      float hf[8];
#pragma unroll
      for (int m = 0; m < 4; ++m) {
        int k = seg * 8 + 2 * m;
        int j = seg * 128 + l16 * 8 + 2 * m;
        float n0 = tanhf_((np[k] - mn) * rsn * lnwL[1024 + j] + lnbL[1024 + j]);
        float n1 = tanhf_((np[k + 1] - mn) * rsn * lnwL[1024 + j + 1] + lnbL[1024 + j + 1]);
        float h0v = (1.f - zv[k]) * n0 + zv[k] * blo(hq[m]);
        float h1v = (1.f - zv[k + 1]) * n1 + zv[k + 1] * bhi(hq[m]);
        if (L1) { h0v += blo(rq[m]); h1v += bhi(rq[m]); }
        outq[m] = bpack(h0v, h1v);
        hf[2 * m] = h0v; hf[2 * m + 1] = h1v;
      }
      *reinterpret_cast<uint4*>(&shA[b2][pc * 8]) =
          make_uint4(outq[0], outq[1], outq[2], outq[3]);
      if (!L1) {
        if (wgl == b2) {  // publish tagged bf16x2 h0 row
          u64* Hw = Hb0 + (size_t)(t & 3) * HSLOT + (size_t)b2 * 256 + seg * 64 + l16 * 4;
#pragma unroll
          for (int m = 0; m < 4; ++m) stA8(&Hw[m], pk(want, outq[m]));
        }
      } else if (wgl == b2) {
        float* Or = out + ((size_t)b2 * TT + t) * 512 + seg * 128 + l16 * 8;
        *reinterpret_cast<float4*>(Or)     = make_float4(hf[0], hf[1], hf[2], hf[3]);
        *reinterpret_cast<float4*>(Or + 4) = make_float4(hf[4], hf[5], hf[6], hf[7]);
      }
    }
    __syncthreads();  // shA(t) complete before next step's matvec
  }
}

// ---------------- launch ----------------
extern "C" void kernel_launch(void* const* d_in, const int* in_sizes, int n_in,
                              void* d_out, int out_size, void* d_ws, size_t ws_size,
                              hipStream_t stream) {
  (void)in_sizes; (void)n_in; (void)out_size; (void)ws_size;
  const float* x   = (const float*)d_in[0];
  const float* Wi  = (const float*)d_in[1];  // [2][1536][512]
  const float* Wh  = (const float*)d_in[2];  // [2][1536][512]
  const float* lnw = (const float*)d_in[3];  // [2][3][512]
  const float* lnb = (const float*)d_in[4];
  float* out = (float*)d_out;

  float* X0 = (float*)d_ws;                      // [24000][1536] f32
  u64* G0  = (u64*)(X0 + (size_t)GM * NG3);      // [2][16][1536]
  u64* G1  = G0 + 2 * BB * NG3;                  // [2][16][2048]
  u64* Hb0 = G1 + 2 * BB * 2048;                 // [4][16][256]
  u32* prog1 = (u32*)(Hb0 + 4 * HSLOT);          // [96][64]

  size_t clear_bytes = (size_t)(2 * BB * NG3 + 2 * BB * 2048 + 4 * HSLOT) * 8 +
                       (size_t)NCW * FL * 4;
  hipMemsetAsync(G0, 0, clear_bytes, stream);

  dim3 ggrid(GM / 64, NG3 / 64);
  gemm_nt<<<ggrid, 256, 0, stream>>>(x, Wi, X0);  // layer-0 input gates
  gru_fused<<<2 * NCW, 256, 0, stream>>>(
      Wh, Wi + (size_t)NG3 * 512, Wh + (size_t)NG3 * 512, X0, lnw, lnb, out,
      G0, G1, Hb0, prog1);
}

// Round 8
// 35751.996 us; speedup vs baseline: 2.0494x; 2.0494x over previous
//
#include <hip/hip_runtime.h>

typedef unsigned long long u64;
typedef unsigned int u32;

#define BB 16
#define TT 1500
#define NG3 1536
#define GM (BB * TT)   /* 24000 */
#define GK 512
#define LNEPS 1e-5f
#define NCW 96         /* compute WGs per layer */
#define FL 64          /* flag line stride in u32 (256B) */
#define HD 8           /* Hb0 ring depth */
#define HROW 256       /* u64 per h row (512 f32 as pairs) */
#define SROW 548       /* f32 stride of LDS h row (137 chunks: bank-shifts rows) */

// ---------------- helpers ----------------
__device__ __forceinline__ float sigmoidf_(float x) { return 1.f / (1.f + __expf(-x)); }
__device__ __forceinline__ float tanhf_(float x) {
  x = fminf(15.f, fmaxf(-15.f, x));
  float e = __expf(2.f * x);
  return (e - 1.f) / (e + 1.f);
}
__device__ __forceinline__ float red16_(float v) {
  v += __shfl_xor(v, 1, 64); v += __shfl_xor(v, 2, 64);
  v += __shfl_xor(v, 4, 64); v += __shfl_xor(v, 8, 64);
  return v;
}
__device__ __forceinline__ float red64_(float v) {
  v += __shfl_xor(v, 1, 64);  v += __shfl_xor(v, 2, 64);
  v += __shfl_xor(v, 4, 64);  v += __shfl_xor(v, 8, 64);
  v += __shfl_xor(v, 16, 64); v += __shfl_xor(v, 32, 64);
  return v;
}
// 16B-chunk swizzle within a row (domain 0..127, bijective per 8-block)
__device__ __forceinline__ int pc(int c) { return c ^ ((c >> 3) & 7); }

__device__ __forceinline__ u64 ldA(const u64* p) {
  return __hip_atomic_load(p, __ATOMIC_RELAXED, __HIP_MEMORY_SCOPE_AGENT);
}
__device__ __forceinline__ void stA8(u64* p, u64 v) {
  __hip_atomic_store(p, v, __ATOMIC_RELAXED, __HIP_MEMORY_SCOPE_AGENT);
}
__device__ __forceinline__ u32 ldA32(const u32* p) {
  return __hip_atomic_load(p, __ATOMIC_RELAXED, __HIP_MEMORY_SCOPE_AGENT);
}
__device__ __forceinline__ void stA32(u32* p, u32 v) {
  __hip_atomic_store(p, v, __ATOMIC_RELAXED, __HIP_MEMORY_SCOPE_AGENT);
}
__device__ __forceinline__ u64 pk(u32 tag, float v) {
  return ((u64)tag << 32) | (u64)__float_as_uint(v);
}
__device__ __forceinline__ u64 pkf2(float lo, float hi) {
  return ((u64)__float_as_uint(hi) << 32) | (u64)__float_as_uint(lo);
}
__device__ __forceinline__ float f2lo(u64 w) { return __uint_as_float((u32)w); }
__device__ __forceinline__ float f2hi(u64 w) { return __uint_as_float((u32)(w >> 32)); }

// ---------------- big GEMM: C[M,N] = A[M,K] @ W[N,K]^T (fp32) ----------------
__global__ __launch_bounds__(256) void gemm_nt(const float* __restrict__ A,
                                               const float* __restrict__ W,
                                               float* __restrict__ C) {
  __shared__ __align__(16) float As[32][68];
  __shared__ __align__(16) float Ws[32][68];
  const int m0 = blockIdx.x * 64;
  const int n0 = blockIdx.y * 64;
  const int tid = threadIdx.x;
  const int tm = tid & 15, tn = tid >> 4;
  float acc[4][4] = {};
  for (int k0 = 0; k0 < GK; k0 += 32) {
#pragma unroll
    for (int u = 0; u < 2; ++u) {
      int idx = tid + u * 256;
      int r = idx >> 3;
      int kq = (idx & 7) * 4;
      float4 a = *reinterpret_cast<const float4*>(&A[(size_t)(m0 + r) * GK + k0 + kq]);
      As[kq + 0][r] = a.x; As[kq + 1][r] = a.y; As[kq + 2][r] = a.z; As[kq + 3][r] = a.w;
      float4 w = *reinterpret_cast<const float4*>(&W[(size_t)(n0 + r) * GK + k0 + kq]);
      Ws[kq + 0][r] = w.x; Ws[kq + 1][r] = w.y; Ws[kq + 2][r] = w.z; Ws[kq + 3][r] = w.w;
    }
    __syncthreads();
#pragma unroll
    for (int kk = 0; kk < 32; ++kk) {
      float a[4], w[4];
      *reinterpret_cast<float4*>(a) = *reinterpret_cast<const float4*>(&As[kk][tm * 4]);
      *reinterpret_cast<float4*>(w) = *reinterpret_cast<const float4*>(&Ws[kk][tn * 4]);
#pragma unroll
      for (int i = 0; i < 4; ++i)
#pragma unroll
        for (int q = 0; q < 4; ++q)
          acc[i][q] = fmaf(a[i], w[q], acc[i][q]);
    }
    __syncthreads();
  }
#pragma unroll
  for (int i = 0; i < 4; ++i) {
    float4 v = make_float4(acc[i][0], acc[i][1], acc[i][2], acc[i][3]);
    *reinterpret_cast<float4*>(&C[(size_t)(m0 + tm * 4 + i) * NG3 + n0 + tn * 4]) = v;
  }
}

// ---------------- fused 2-layer GRU scan, role-split ----------------
// WG 0..95   : L0 compute (16 cols Wh0, f32 regs)
// WG 96..191 : L1 compute (16 cols Wh1 + Wi1, dual matvec)
// WG 192..207: L0 updater b (single wave, h in f32 regs)
// WG 208..223: L1 updater b (single wave, + residual + out write)
// G0 u64[16][1536], G1 u64[16][2048] (1536..: x_n): per-value tagged (tag=t+1).
// Hb0 u64[8][16][256], Hb1 u64[2][16][256]: UNtagged f32-pair h rows; readiness
// via h0tag/h1tag row flags published after producer vmcnt(0) drain.
__global__ __launch_bounds__(256, 1) void gru_fused(
    const float* __restrict__ Wh0, const float* __restrict__ Wi1,
    const float* __restrict__ Wh1, const float* __restrict__ X0,
    const float* __restrict__ lnw, const float* __restrict__ lnb,
    float* __restrict__ out, u64* __restrict__ G0, u64* __restrict__ G1,
    u64* __restrict__ Hb0, u64* __restrict__ Hb1, u32* __restrict__ tags) {
  u32* h0tag = tags;            // [16] * FL
  u32* h1tag = tags + 16 * FL;  // [16] * FL

  __shared__ __align__(16) float shA[BB][SROW];  // this layer's h(t-1)
  __shared__ __align__(16) float shB[BB][SROW];  // L1: h0(t)

  const int tid = threadIdx.x, wg = blockIdx.x;
  const int lane = tid & 63, wv = tid >> 6;

  if (wg < 2 * NCW) {
    // ================= COMPUTE WGs =================
    const bool L1 = wg >= NCW;
    const int wgl = L1 ? wg - NCW : wg;
    const int ks = lane & 15, cq = lane >> 4;
    const int col = wgl * 16 + wv * 4 + cq;
    const int rr = tid >> 4, q16 = tid & 15;  // h-copy: row / 32-col group

    float wh[32], wi[32];
    {
      const float* Wp = (L1 ? Wh1 : Wh0) + (size_t)col * 512 + ks * 32;
#pragma unroll
      for (int q = 0; q < 8; ++q) *(float4*)&wh[q * 4] = *(const float4*)&Wp[q * 4];
      if (L1) {
        const float* Wq = Wi1 + (size_t)col * 512 + ks * 32;
#pragma unroll
        for (int q = 0; q < 8; ++q) *(float4*)&wi[q * 4] = *(const float4*)&Wq[q * 4];
      } else {
#pragma unroll
        for (int q = 0; q < 32; ++q) wi[q] = 0.f;
      }
    }
    for (int idx = tid; idx < BB * SROW; idx += 256) {
      (&shA[0][0])[idx] = 0.f; (&shB[0][0])[idx] = 0.f;
    }
    __syncthreads();

    u64* Gb = L1 ? G1 : G0;
    const int GW = L1 ? 2048 : 1536;

    for (int t = 0; t < TT; ++t) {
      const u32 want = (u32)(t + 1);
      // ---- wait for h row flags, then copy h rows into LDS (f32, swizzled) ----
      if (!L1) {
        if (t > 0) {
          if (tid < 16)
            while (ldA32(&h0tag[(size_t)tid * FL]) < (u32)t) __builtin_amdgcn_s_sleep(1);
          __syncthreads();
          const u64* src = Hb0 + (size_t)((t - 1) & (HD - 1)) * (BB * HROW) +
                           (size_t)rr * HROW + q16 * 16;
          float v[32];
#pragma unroll
          for (int m = 0; m < 16; ++m) { u64 w = ldA(src + m); v[2*m] = f2lo(w); v[2*m+1] = f2hi(w); }
#pragma unroll
          for (int w = 0; w < 8; ++w)
            *(float4*)&shA[rr][pc(q16 * 8 + w) * 4] = *(float4*)&v[w * 4];
          __syncthreads();
        }
      } else {
        if (tid < 16)
          while (ldA32(&h0tag[(size_t)tid * FL]) < want) __builtin_amdgcn_s_sleep(1);
        if (t > 0 && tid >= 16 && tid < 32)
          while (ldA32(&h1tag[(size_t)(tid - 16) * FL]) < (u32)t) __builtin_amdgcn_s_sleep(1);
        __syncthreads();
        {
          const u64* src = Hb0 + (size_t)(t & (HD - 1)) * (BB * HROW) +
                           (size_t)rr * HROW + q16 * 16;
          float v[32];
#pragma unroll
          for (int m = 0; m < 16; ++m) { u64 w = ldA(src + m); v[2*m] = f2lo(w); v[2*m+1] = f2hi(w); }
#pragma unroll
          for (int w = 0; w < 8; ++w)
            *(float4*)&shB[rr][pc(q16 * 8 + w) * 4] = *(float4*)&v[w * 4];
        }
        if (t > 0) {
          const u64* src = Hb1 + (size_t)((t - 1) & 1) * (BB * HROW) +
                           (size_t)rr * HROW + q16 * 16;
          float v[32];
#pragma unroll
          for (int m = 0; m < 16; ++m) { u64 w = ldA(src + m); v[2*m] = f2lo(w); v[2*m+1] = f2hi(w); }
#pragma unroll
          for (int w = 0; w < 8; ++w)
            *(float4*)&shA[rr][pc(q16 * 8 + w) * 4] = *(float4*)&v[w * 4];
        }
        __syncthreads();
      }

      // ---- matvec(s): thread = (K-chunk ks, col); reduce over 16 lanes ----
      float gh = 0.f, gx = 0.f;
#pragma unroll 2
      for (int b = 0; b < 16; ++b) {
        float p = 0.f, p2 = 0.f;
#pragma unroll
        for (int j = 0; j < 8; ++j) {
          const int off = pc(ks * 8 + j) * 4;
          float4 a = *(const float4*)&shA[b][off];
          p = fmaf(a.x, wh[j*4+0], p); p = fmaf(a.y, wh[j*4+1], p);
          p = fmaf(a.z, wh[j*4+2], p); p = fmaf(a.w, wh[j*4+3], p);
          if (L1) {
            float4 c = *(const float4*)&shB[b][off];
            p2 = fmaf(c.x, wi[j*4+0], p2); p2 = fmaf(c.y, wi[j*4+1], p2);
            p2 = fmaf(c.z, wi[j*4+2], p2); p2 = fmaf(c.w, wi[j*4+3], p2);
          }
        }
        p = red16_(p);
        if (L1) p2 = red16_(p2);
        if (ks == b) { gh = p; gx = p2; }
      }
      // ---- tagged gate store (fire-and-forget) ----
      u64* Gw = Gb + (size_t)ks * GW;
      if (!L1) {
        stA8(&Gw[col], pk(want, gh));
      } else if (col < 1024) {
        stA8(&Gw[col], pk(want, gh + gx));
      } else {
        stA8(&Gw[col], pk(want, gh));        // h_n
        stA8(&Gw[col + 512], pk(want, gx));  // x_n
      }
    }
  } else {
    // ================= UPDATER WGs (single wave) =================
    if (wv != 0) return;
    const bool L1u = wg >= 2 * NCW + 16;
    const int b = wg - (L1u ? 2 * NCW + 16 : 2 * NCW);
    const float* lnwL = lnw + (L1u ? 1536 : 0);
    const float* lnbL = lnb + (L1u ? 1536 : 0);
    const int j8 = lane * 8;
    const u64* Gr = (L1u ? G1 : G0) + (size_t)b * (L1u ? 2048 : 1536);

    float lw0[8], lb0[8], lw1[8], lb1[8], lw2[8], lb2[8];
#pragma unroll
    for (int q = 0; q < 8; ++q) {
      lw0[q] = lnwL[j8 + q];        lb0[q] = lnbL[j8 + q];
      lw1[q] = lnwL[512 + j8 + q];  lb1[q] = lnbL[512 + j8 + q];
      lw2[q] = lnwL[1024 + j8 + q]; lb2[q] = lnbL[1024 + j8 + q];
    }
    float h[8];
#pragma unroll
    for (int q = 0; q < 8; ++q) h[q] = 0.f;

    for (int t = 0; t < TT; ++t) {
      const u32 want = (u32)(t + 1);
      // L0: prefetch X row (plain cached loads, immutable)
      float xr[8], xz[8], xnl[8];
      if (!L1u) {
        const float* Xr = X0 + ((size_t)b * TT + t) * NG3;
#pragma unroll
        for (int q = 0; q < 8; q += 4) {
          *(float4*)&xr[q]  = *(const float4*)&Xr[j8 + q];
          *(float4*)&xz[q]  = *(const float4*)&Xr[512 + j8 + q];
          *(float4*)&xnl[q] = *(const float4*)&Xr[1024 + j8 + q];
        }
        // throttle Hb0 ring slot t&7 overwrite: L1 must have finished step t-8
        if (t >= HD) {
          const u32 w2 = (u32)(t - (HD - 1));
          for (;;) {
            bool ok = (lane < 16) ? (ldA32(&h1tag[(size_t)lane * FL]) >= w2) : true;
            if (__all(ok)) break;
            __builtin_amdgcn_s_sleep(2);
          }
        }
      }
      // ---- poll own tagged gate row ----
      float gr[8], gz[8], hn[8], xn[8];
      for (;;) {
        u32 bad = 0;
#pragma unroll
        for (int e = 0; e < 8; ++e) {
          u64 a = ldA(&Gr[j8 + e]);
          u64 c = ldA(&Gr[512 + j8 + e]);
          u64 d = ldA(&Gr[1024 + j8 + e]);
          gr[e] = f2lo(a); gz[e] = f2lo(c); hn[e] = f2lo(d);
          bad |= ((u32)(a >> 32) ^ want) | ((u32)(c >> 32) ^ want) | ((u32)(d >> 32) ^ want);
          if (L1u) {
            u64 x = ldA(&Gr[1536 + j8 + e]);
            xn[e] = f2lo(x);
            bad |= (u32)(x >> 32) ^ want;
          }
        }
        if (!bad) break;
        __builtin_amdgcn_s_sleep(1);
      }
      float res[8];
      if (!L1u) {
#pragma unroll
        for (int e = 0; e < 8; ++e) { gr[e] += xr[e]; gz[e] += xz[e]; xn[e] = xnl[e]; }
      } else {
        // residual h0(t): guaranteed resident (L1-compute consumed it already)
        const u64* Hr = Hb0 + (size_t)(t & (HD - 1)) * (BB * HROW) + (size_t)b * HROW + lane * 4;
#pragma unroll
        for (int m = 0; m < 4; ++m) { u64 w = ldA(Hr + m); res[2*m] = f2lo(w); res[2*m+1] = f2hi(w); }
      }
      // ---- LN r -> rv ----
      float s = 0.f, s2 = 0.f;
#pragma unroll
      for (int q = 0; q < 8; ++q) { s += gr[q]; s2 += gr[q] * gr[q]; }
      s = red64_(s); s2 = red64_(s2);
      float m = s * (1.f / 512.f);
      float rs = rsqrtf(s2 * (1.f / 512.f) - m * m + LNEPS);
      float rv[8];
#pragma unroll
      for (int q = 0; q < 8; ++q) rv[q] = sigmoidf_((gr[q] - m) * rs * lw0[q] + lb0[q]);
      // ---- LN z -> zv ----
      s = 0.f; s2 = 0.f;
#pragma unroll
      for (int q = 0; q < 8; ++q) { s += gz[q]; s2 += gz[q] * gz[q]; }
      s = red64_(s); s2 = red64_(s2);
      m = s * (1.f / 512.f);
      rs = rsqrtf(s2 * (1.f / 512.f) - m * m + LNEPS);
      float zv[8];
#pragma unroll
      for (int q = 0; q < 8; ++q) zv[q] = sigmoidf_((gz[q] - m) * rs * lw1[q] + lb1[q]);
      // ---- n pre-act + LN ----
      float np[8];
      s = 0.f; s2 = 0.f;
#pragma unroll
      for (int q = 0; q < 8; ++q) {
        np[q] = xn[q] + rv[q] * hn[q];
        s += np[q]; s2 += np[q] * np[q];
      }
      s = red64_(s); s2 = red64_(s2);
      m = s * (1.f / 512.f);
      rs = rsqrtf(s2 * (1.f / 512.f) - m * m + LNEPS);
      // ---- h update (f32 history in regs) ----
#pragma unroll
      for (int q = 0; q < 8; ++q) {
        float n = tanhf_((np[q] - m) * rs * lw2[q] + lb2[q]);
        h[q] = (1.f - zv[q]) * n + zv[q] * h[q];
        if (L1u) h[q] += res[q];
      }
      // ---- publish h row (untagged f32 pairs) + drain + flag ----
      u64* Hw = (L1u ? Hb1 + (size_t)(t & 1) * (BB * HROW)
                     : Hb0 + (size_t)(t & (HD - 1)) * (BB * HROW)) +
                (size_t)b * HROW + lane * 4;
#pragma unroll
      for (int mq = 0; mq < 4; ++mq) stA8(&Hw[mq], pkf2(h[2*mq], h[2*mq+1]));
      if (L1u) {
        float* Or = out + ((size_t)b * TT + t) * 512 + j8;
        *(float4*)&Or[0] = make_float4(h[0], h[1], h[2], h[3]);
        *(float4*)&Or[4] = make_float4(h[4], h[5], h[6], h[7]);
      }
      asm volatile("s_waitcnt vmcnt(0)" ::: "memory");
      if (lane == 0) stA32(&(L1u ? h1tag : h0tag)[(size_t)b * FL], want);
    }
  }
}

// ---------------- launch ----------------
extern "C" void kernel_launch(void* const* d_in, const int* in_sizes, int n_in,
                              void* d_out, int out_size, void* d_ws, size_t ws_size,
                              hipStream_t stream) {
  (void)in_sizes; (void)n_in; (void)out_size; (void)ws_size;
  const float* x   = (const float*)d_in[0];
  const float* Wi  = (const float*)d_in[1];  // [2][1536][512]
  const float* Wh  = (const float*)d_in[2];  // [2][1536][512]
  const float* lnw = (const float*)d_in[3];  // [2][3][512]
  const float* lnb = (const float*)d_in[4];
  float* out = (float*)d_out;

  float* X0 = (float*)d_ws;                  // [24000][1536] f32
  u64* G0  = (u64*)(X0 + (size_t)GM * NG3);  // [16][1536]
  u64* G1  = G0 + BB * NG3;                  // [16][2048]
  u64* Hb0 = G1 + BB * 2048;                 // [8][16][256]
  u64* Hb1 = Hb0 + HD * BB * HROW;           // [2][16][256]
  u32* tags = (u32*)(Hb1 + 2 * BB * HROW);   // 32 * FL

  size_t clear_bytes = (size_t)(BB * NG3 + BB * 2048 + HD * BB * HROW + 2 * BB * HROW) * 8 +
                       (size_t)32 * FL * 4;
  hipMemsetAsync(G0, 0, clear_bytes, stream);

  dim3 ggrid(GM / 64, NG3 / 64);
  gemm_nt<<<ggrid, 256, 0, stream>>>(x, Wi, X0);  // layer-0 input gates
  gru_fused<<<2 * NCW + 32, 256, 0, stream>>>(
      Wh, Wi + (size_t)NG3 * 512, Wh + (size_t)NG3 * 512, X0, lnw, lnb, out,
      G0, G1, Hb0, Hb1, tags);
}